// Round 3
// baseline (209.456 us; speedup 1.0000x reference)
//
#include <hip/hip_runtime.h>
#include <hip/hip_cooperative_groups.h>

namespace cg = cooperative_groups;

// CenterNeighAtt on MI355X. E=512, F=256, R=4.
//
// Exact math simplifications (validated R1/R2, absmax ~5e-4 vs 2.3e-3 threshold):
//  * alpha = softmax_j(sum_i scores[i,j]) is uniform 1/E: sum_i attention[i,j,f]==1,
//    so column sums of scores are constant in j. lin_w/lin_b are dead inputs.
//  * No max-subtraction in softmaxes: logits bounded (~20), exp far below f32 overflow.
//
// R3 structure: single cooperative kernel (R2 evidence: 5 dispatches ~= 25-30us of
// launch overhead dominated the 49.6us total). 512 blocks x 256 threads, 3 grid syncs.
//  P1: zero Z/Hp; s[i,:] = softmax_j(sum_r adj[r,i,:])   (block = row i)
//  P2: Z[j,f] += sum_{i in chunk} exp2(lrelu(s*h_if*h_jf)*log2e)   (atomicAdd)
//  P3: Hp[i,f] += sum_{j in chunk} (h_jf/Z[j,f]) * exp2(...)        (atomicAdd, g inline)
//  P4: out = elu(Hp); alpha = 1/E

#define EE 512
#define FF 256
#define RRR 4
#define LOG2E 1.44269504088896340736f
#define TT 8     // rows per block in P2/P3
#define CLEN 64  // reduction chunk length (512/8)
#define NBLK 512

__global__ __launch_bounds__(256, 2) void fused(const float* __restrict__ h,
                                                const float* __restrict__ adj,
                                                float* __restrict__ s,
                                                float* __restrict__ Z,
                                                float* __restrict__ Hp,
                                                float* __restrict__ out) {
    cg::grid_group grid = cg::this_grid();
    const int b = blockIdx.x;
    const int t = threadIdx.x;
    __shared__ float smem[CLEN * TT];   // 512 floats; P1 uses first 256 for reduction

    // ---------------- P1: zero accumulators + s row-softmax ----------------
    Z[b * 256 + t]  = 0.f;   // Z:  E*F = 131072 floats, covered exactly
    Hp[b * 256 + t] = 0.f;   // Hp: E*F
    {
        const int i = b;
        const float* base = adj + (size_t)i * EE;
        float t0 = 0.f, t1 = 0.f;
#pragma unroll
        for (int r = 0; r < RRR; ++r) {
            t0 += base[(size_t)r * EE * EE + t];
            t1 += base[(size_t)r * EE * EE + t + 256];
        }
        const float e0 = __expf(t0);
        const float e1 = __expf(t1);
        smem[t] = e0 + e1;
        __syncthreads();
        for (int off = 128; off > 0; off >>= 1) {
            if (t < off) smem[t] += smem[t + off];
            __syncthreads();
        }
        const float inv = 1.0f / smem[0];
        s[(size_t)i * EE + t]       = e0 * inv;
        s[(size_t)i * EE + t + 256] = e1 * inv;
    }
    grid.sync();

    // ---------------- P2: partial softmax denominators over i-chunks -------
    {
        const int jg = b >> 3;            // 64 j-groups
        const int c  = b & 7;             // 8 i-chunks
        const int j0 = jg * TT;
        const int i0 = c * CLEN;
        const int f  = t;
        for (int idx = t; idx < CLEN * TT; idx += 256)          // sl[ii][tj]
            smem[idx] = s[(size_t)(i0 + (idx >> 3)) * EE + j0 + (idx & 7)];
        __syncthreads();
        float hj[TT], Zl[TT];
#pragma unroll
        for (int tj = 0; tj < TT; ++tj) {
            hj[tj] = h[(size_t)(j0 + tj) * FF + f] * LOG2E;     // fold log2e
            Zl[tj] = 0.f;
        }
#pragma unroll 8
        for (int ii = 0; ii < CLEN; ++ii) {
            const float hif = h[(size_t)(i0 + ii) * FF + f];
#pragma unroll
            for (int tj = 0; tj < TT; ++tj) {
                const float y = smem[ii * TT + tj] * hif * hj[tj];
                const float z = fmaxf(y, 0.2f * y);             // lrelu (log2e-scaled)
                Zl[tj] += __builtin_amdgcn_exp2f(z);
            }
        }
#pragma unroll
        for (int tj = 0; tj < TT; ++tj)
            atomicAdd(&Z[(size_t)(j0 + tj) * FF + f], Zl[tj]);
    }
    grid.sync();

    // ---------------- P3: numerators over j-chunks (g = h/Z inline) --------
    {
        const int ig = b >> 3;
        const int c  = b & 7;
        const int i0 = ig * TT;
        const int j0 = c * CLEN;
        const int f  = t;
        for (int idx = t; idx < CLEN * TT; idx += 256)          // sl[jj][ti]
            smem[idx] = s[(size_t)(i0 + (idx & 7)) * EE + j0 + (idx >> 3)];
        __syncthreads();
        float hl[TT], acc[TT];
#pragma unroll
        for (int ti = 0; ti < TT; ++ti) {
            hl[ti] = h[(size_t)(i0 + ti) * FF + f] * LOG2E;
            acc[ti] = 0.f;
        }
#pragma unroll 8
        for (int jj = 0; jj < CLEN; ++jj) {
            const float hjf = h[(size_t)(j0 + jj) * FF + f];
            const float gj  = hjf * __builtin_amdgcn_rcpf(Z[(size_t)(j0 + jj) * FF + f]);
#pragma unroll
            for (int ti = 0; ti < TT; ++ti) {
                const float y = smem[jj * TT + ti] * hl[ti] * hjf;
                const float z = fmaxf(y, 0.2f * y);
                acc[ti] = fmaf(__builtin_amdgcn_exp2f(z), gj, acc[ti]);
            }
        }
#pragma unroll
        for (int ti = 0; ti < TT; ++ti)
            atomicAdd(&Hp[(size_t)(i0 + ti) * FF + f], acc[ti]);
    }
    grid.sync();

    // ---------------- P4: ELU + alpha --------------------------------------
    {
        const float a = Hp[b * 256 + t];
        out[b * 256 + t] = (a > 0.f) ? a : (__expf(a) - 1.0f);
        if (b == 0) {
            out[EE * FF + t]       = 1.0f / EE;   // alpha: softmax of constant = uniform
            out[EE * FF + 256 + t] = 1.0f / EE;
        }
    }
}

extern "C" void kernel_launch(void* const* d_in, const int* in_sizes, int n_in,
                              void* d_out, int out_size, void* d_ws, size_t ws_size,
                              hipStream_t stream) {
    const float* h   = (const float*)d_in[0];  // [E,F]
    const float* adj = (const float*)d_in[1];  // [R,E,E]
    // lin_w / lin_b mathematically dead (alpha uniform).

    float* s  = (float*)d_ws;                  // 1 MB
    float* Z  = s + (size_t)EE * EE;           // 512 KB
    float* Hp = Z + (size_t)EE * FF;           // 512 KB (total 2 MB)
    float* out = (float*)d_out;

    void* args[] = { (void*)&h, (void*)&adj, (void*)&s, (void*)&Z, (void*)&Hp, (void*)&out };
    hipLaunchCooperativeKernel((void*)fused, dim3(NBLK), dim3(256), args, 0, stream);
}

// Round 4
// 44.801 us; speedup vs baseline: 4.6752x; 4.6752x over previous
//
#include <hip/hip_runtime.h>

// CenterNeighAtt on MI355X. E=512, F=256, R=4.
//
// Exact math simplifications (validated R1-R3, absmax ~5e-4 vs 2.3e-3 threshold):
//  * alpha = softmax_j(sum_i scores[i,j]) is uniform 1/E: sum_i attention[i,j,f]==1,
//    so column sums of scores are constant in j. lin_w/lin_b are dead inputs.
//  * No max-subtraction in softmaxes: logits bounded (~20), exp far below f32 overflow.
//
// R4: R3's cooperative grid.sync cost ~55us each (196us total, VALUBusy 11.8% ->
// only ~23us of real work). Back to 4 stream-ordered kernels; kernel boundaries
// provide the Z/Hp barriers. atomicAdd split-K replaces the R2 reduction kernels.
// LDS s-tile stored as float4 and read as ds_read_b128 broadcasts (R2's scalar
// ds_read_b32 per element was ~10us/pass of hidden LDS issue cost).

#define EE 512
#define FF 256
#define RRR 4
#define LOG2E 1.44269504088896340736f
#define TT 8     // rows per block in kB/kC
#define NCH 8    // reduction-axis chunks
#define CLEN 64  // 512 / NCH

// --- kA: zero Z/Hp; s[i,:] = softmax_j(sum_r adj[r,i,:]); alpha ------------
__global__ __launch_bounds__(256) void kA(const float* __restrict__ adj,
                                          float* __restrict__ s,
                                          float* __restrict__ Z,
                                          float* __restrict__ Hp,
                                          float* __restrict__ out) {
    const int i = blockIdx.x;
    const int t = threadIdx.x;
    Z[i * 256 + t]  = 0.f;           // E*F floats, covered exactly by grid
    Hp[i * 256 + t] = 0.f;
    if (i == 0) {                    // alpha: softmax of constant vector = 1/E
        out[EE * FF + t]       = 1.0f / EE;
        out[EE * FF + 256 + t] = 1.0f / EE;
    }
    const float* base = adj + (size_t)i * EE;
    float t0 = 0.f, t1 = 0.f;
#pragma unroll
    for (int r = 0; r < RRR; ++r) {
        t0 += base[(size_t)r * EE * EE + t];
        t1 += base[(size_t)r * EE * EE + t + 256];
    }
    const float e0 = __expf(t0);
    const float e1 = __expf(t1);
    __shared__ float red[256];
    red[t] = e0 + e1;
    __syncthreads();
    for (int off = 128; off > 0; off >>= 1) {
        if (t < off) red[t] += red[t + off];
        __syncthreads();
    }
    const float inv = 1.0f / red[0];
    s[(size_t)i * EE + t]       = e0 * inv;
    s[(size_t)i * EE + t + 256] = e1 * inv;
}

// --- kB: Z[j,f] += sum_{i in chunk c} exp2(lrelu(s*h_if*h_jf)*log2e) -------
__global__ __launch_bounds__(256) void kB(const float* __restrict__ h,
                                          const float* __restrict__ s,
                                          float* __restrict__ Z) {
    const int j0 = blockIdx.x * TT;   // 64 j-groups
    const int c  = blockIdx.y;        // 8 i-chunks
    const int i0 = c * CLEN;
    const int f  = threadIdx.x;
    __shared__ float4 sl4[CLEN * 2];  // sl[ii][0..7] as two float4 per row
    if (f < CLEN * 2) {               // row ii = f>>1, half p = f&1 (16B-aligned: EE,j0 mult of 8)
        sl4[f] = ((const float4*)(s + (size_t)(i0 + (f >> 1)) * EE + j0))[f & 1];
    }
    __syncthreads();
    float hj[TT], Zl[TT];
#pragma unroll
    for (int tj = 0; tj < TT; ++tj) {
        hj[tj] = h[(size_t)(j0 + tj) * FF + f] * LOG2E;  // fold log2e into one factor
        Zl[tj] = 0.f;
    }
#pragma unroll 4
    for (int ii = 0; ii < CLEN; ++ii) {
        const float hif = h[(size_t)(i0 + ii) * FF + f];
        const float4 sa = sl4[ii * 2];       // ds_read_b128 broadcast (conflict-free)
        const float4 sb = sl4[ii * 2 + 1];
        float sv[8] = {sa.x, sa.y, sa.z, sa.w, sb.x, sb.y, sb.z, sb.w};
#pragma unroll
        for (int tj = 0; tj < TT; ++tj) {
            const float y = sv[tj] * hif * hj[tj];
            const float z = fmaxf(y, 0.2f * y);          // lrelu (log2e-scaled)
            Zl[tj] += __builtin_amdgcn_exp2f(z);
        }
    }
#pragma unroll
    for (int tj = 0; tj < TT; ++tj)
        atomicAdd(&Z[(size_t)(j0 + tj) * FF + f], Zl[tj]);
}

// --- kC: Hp[i,f] += sum_{j in chunk c} (h_jf*rcp(Z_jf)) * exp2(...) --------
__global__ __launch_bounds__(256) void kC(const float* __restrict__ h,
                                          const float* __restrict__ s,
                                          const float* __restrict__ Z,
                                          float* __restrict__ Hp) {
    const int i0 = blockIdx.x * TT;   // 64 i-groups
    const int c  = blockIdx.y;        // 8 j-chunks
    const int j0 = c * CLEN;
    const int f  = threadIdx.x;
    __shared__ float4 sl4[CLEN * 2];  // sl[jj][ti]: transposed gather, rows of 8 ti
    {
        __shared__ float slf[CLEN * TT];
        for (int idx = f; idx < CLEN * TT; idx += 256)   // slf[jj*8+ti]
            slf[idx] = s[(size_t)(i0 + (idx & 7)) * EE + j0 + (idx >> 3)];
        __syncthreads();
        if (f < CLEN * 2) sl4[f] = ((const float4*)slf)[f];
    }
    __syncthreads();
    float hl[TT], acc[TT];
#pragma unroll
    for (int ti = 0; ti < TT; ++ti) {
        hl[ti] = h[(size_t)(i0 + ti) * FF + f] * LOG2E;
        acc[ti] = 0.f;
    }
#pragma unroll 4
    for (int jj = 0; jj < CLEN; ++jj) {
        const float hjf = h[(size_t)(j0 + jj) * FF + f];
        const float gj  = hjf * __builtin_amdgcn_rcpf(Z[(size_t)(j0 + jj) * FF + f]);
        const float4 sa = sl4[jj * 2];
        const float4 sb = sl4[jj * 2 + 1];
        float sv[8] = {sa.x, sa.y, sa.z, sa.w, sb.x, sb.y, sb.z, sb.w};
#pragma unroll
        for (int ti = 0; ti < TT; ++ti) {
            const float y = sv[ti] * hl[ti] * hjf;
            const float z = fmaxf(y, 0.2f * y);
            acc[ti] = fmaf(__builtin_amdgcn_exp2f(z), gj, acc[ti]);
        }
    }
#pragma unroll
    for (int ti = 0; ti < TT; ++ti)
        atomicAdd(&Hp[(size_t)(i0 + ti) * FF + f], acc[ti]);
}

// --- kC2: out = elu(Hp) ----------------------------------------------------
__global__ __launch_bounds__(256) void kC2(const float* __restrict__ Hp,
                                           float* __restrict__ out) {
    const int i = blockIdx.x, f = threadIdx.x;
    const float a = Hp[i * 256 + f];
    out[i * 256 + f] = (a > 0.f) ? a : (__expf(a) - 1.0f);
}

extern "C" void kernel_launch(void* const* d_in, const int* in_sizes, int n_in,
                              void* d_out, int out_size, void* d_ws, size_t ws_size,
                              hipStream_t stream) {
    const float* h   = (const float*)d_in[0];  // [E,F]
    const float* adj = (const float*)d_in[1];  // [R,E,E]
    // lin_w / lin_b mathematically dead (alpha uniform).

    float* s  = (float*)d_ws;                  // 1 MB
    float* Z  = s + (size_t)EE * EE;           // 512 KB
    float* Hp = Z + (size_t)EE * FF;           // 512 KB (total 2 MB)
    float* out = (float*)d_out;

    kA <<<EE, 256, 0, stream>>>(adj, s, Z, Hp, out);
    kB <<<dim3(EE / TT, NCH), 256, 0, stream>>>(h, s, Z);
    kC <<<dim3(EE / TT, NCH), 256, 0, stream>>>(h, s, Z, Hp);
    kC2<<<EE, 256, 0, stream>>>(Hp, out);
}